// Round 3
// baseline (39.788 us; speedup 1.0000x reference)
//
#include <hip/hip_runtime.h>

// GraphUpSamplingLayer: 3-D k=1 NN argmin + batched feature gather.
// B=4, C=512, M=2048 (coarse points), N=8192 (dense points), D=3.
constexpr int B = 4;
constexpr int C = 512;
constexpr int M = 2048;
constexpr int N = 8192;

// ---------------------------------------------------------------------------
// Phase 1: idx[b][n] = argmin_m ||pos[b][n] - sub_pos[b][m]||^2
//
// f32 difference-form distance (proven vs np ref: absmax 0.0 in R1/R2).
//
// R2 post-mortem: 512 blocks = 2 waves/SIMD could not hide the ds_read
// latency (argmin ~28us vs 7.7us VALU floor). This version:
//   P=32 lanes/query, Q=4 queries/thread -> 32 queries/block
//   -> 1024 blocks = 4 waves/SIMD (2x occupancy)
//   -> LDS traffic still 4 B/pair (one float4 feeds 4 query-pairs)
//   -> explicit 1-deep prefetch: next iter's ds_read issues before this
//      iter's 36-VALU body.
// Loop: M/32 = 64 iters. Reduction: 5 shfl_xor steps within each aligned
// 32-lane group.
// ---------------------------------------------------------------------------
__global__ __launch_bounds__(256) void nn_argmin_kernel(
    const float* __restrict__ pos,      // [B][N][3]
    const float* __restrict__ sub_pos,  // [B][M][3]
    int* __restrict__ idx_out)          // [B][N]
{
    __shared__ float4 sp[M];            // 32 KB: (x,y,z,pad)

    const int b  = blockIdx.x >> 8;     // 256 blocks per batch
    const int n0 = (blockIdx.x & 255) << 5;  // 32 queries per block
    const int t  = threadIdx.x;

    const float* spb = sub_pos + (size_t)b * (M * 3);
    #pragma unroll
    for (int i = t; i < M; i += 256) {
        sp[i] = make_float4(spb[i * 3 + 0], spb[i * 3 + 1], spb[i * 3 + 2], 0.f);
    }
    __syncthreads();

    const int part = t & 31;            // candidate slice within the 32-lane group
    const int g    = t >> 5;            // query group (8 per block)
    const int nbase = n0 + g * 4;       // this thread's 4 queries

    float px[4], py[4], pz[4], best[4];
    int bidx[4];
    #pragma unroll
    for (int q = 0; q < 4; ++q) {
        const float* pp = pos + ((size_t)b * N + nbase + q) * 3;
        px[q] = pp[0]; py[q] = pp[1]; pz[q] = pp[2];
        best[q] = 1e30f;
        bidx[q] = M;
    }

    constexpr int IT = M / 32;          // 64
    float4 s = sp[part];                // prefetch iter 0
    #pragma unroll 4
    for (int i = 0; i < IT; ++i) {
        const float4 cur = s;
        // prefetch next iter (wraps harmlessly on the last one)
        s = sp[((((i + 1) & (IT - 1)) << 5) + part)];
        const int m = (i << 5) + part;
        #pragma unroll
        for (int q = 0; q < 4; ++q) {
            const float dx = px[q] - cur.x;
            const float dy = py[q] - cur.y;
            const float dz = pz[q] - cur.z;
            const float d = dx * dx + dy * dy + dz * dz;
            if (d < best[q]) { best[q] = d; bidx[q] = m; }  // strict <: first idx
        }
    }

    // argmin-reduce across the 32 parts; exact ties -> smaller global index
    // (jnp.argmin first-occurrence semantics). xor offsets < 32 keep lanes
    // within their aligned 32-lane group.
    #pragma unroll
    for (int off = 1; off < 32; off <<= 1) {
        #pragma unroll
        for (int q = 0; q < 4; ++q) {
            const float ob = __shfl_xor(best[q], off, 64);
            const int   oi = __shfl_xor(bidx[q], off, 64);
            if (ob < best[q] || (ob == best[q] && oi < bidx[q])) {
                best[q] = ob; bidx[q] = oi;
            }
        }
    }
    if (part == 0) {
        #pragma unroll
        for (int q = 0; q < 4; ++q)
            idx_out[(size_t)b * N + nbase + q] = bidx[q];
    }
}

// ---------------------------------------------------------------------------
// Phase 2: out[b][c][n] = sub_x[b][c][idx[b][n]]
// HBM-roofline bound (64 MB write + 16 MB read ~= 12.7 us floor); unchanged.
// ---------------------------------------------------------------------------
__global__ __launch_bounds__(256) void gather_kernel(
    const float* __restrict__ sub_x,  // [B][C][M]
    const int* __restrict__ idx,      // [B][N]
    float* __restrict__ out)          // [B][C][N]
{
    __shared__ float row[M];          // 8 KB

    const int b = blockIdx.x >> 9;    // C = 512
    const int c = blockIdx.x & 511;
    const int t = threadIdx.x;

    const float* rsrc = sub_x + ((size_t)b * C + c) * M;
    for (int i = t; i < M; i += 256) row[i] = rsrc[i];
    __syncthreads();

    const int4* iv = (const int4*)(idx + (size_t)b * N);
    float4* ov = (float4*)(out + ((size_t)b * C + c) * N);
    #pragma unroll
    for (int i = t; i < N / 4; i += 256) {
        const int4 ii = iv[i];
        float4 v;
        v.x = row[ii.x];
        v.y = row[ii.y];
        v.z = row[ii.z];
        v.w = row[ii.w];
        ov[i] = v;
    }
}

extern "C" void kernel_launch(void* const* d_in, const int* in_sizes, int n_in,
                              void* d_out, int out_size, void* d_ws, size_t ws_size,
                              hipStream_t stream) {
    const float* sub_x   = (const float*)d_in[0];  // [B][C][M]
    const float* sub_pos = (const float*)d_in[1];  // [B][M][3]
    const float* pos     = (const float*)d_in[2];  // [B][N][3]
    float* out = (float*)d_out;                    // [B][C][N]
    int* idx = (int*)d_ws;                         // B*N*4 = 128 KB scratch

    nn_argmin_kernel<<<B * (N / 32), 256, 0, stream>>>(pos, sub_pos, idx);
    gather_kernel<<<B * C, 256, 0, stream>>>(sub_x, idx, out);
}